// Round 3
// baseline (148.805 us; speedup 1.0000x reference)
//
#include <hip/hip_runtime.h>
#include <hip/hip_bf16.h>
#include <cmath>

#define NN 8192
#define FIN 512
#define FD 64
#define IT 16            // rows per k_attn block
#define JC 128           // j-chunk (4 waves x 32 k)
#define NCH (NN / JC)    // 64 chunks

typedef __attribute__((ext_vector_type(4))) float f32x4;
typedef __attribute__((ext_vector_type(8))) short s16x8;

static __device__ __forceinline__ s16x8 as_s16x8(int4 v) {
    s16x8 r; __builtin_memcpy(&r, &v, 16); return r;
}
static __device__ __forceinline__ short bf16bits(float f) {
    __hip_bfloat16 h = __float2bfloat16(f);
    short s; __builtin_memcpy(&s, &h, 2); return s;
}

// ---------------- kernel 1: h = x@W (bf16, transposed) ; src/dst -------------
__global__ __launch_bounds__(256) void k_proj(const float* __restrict__ x,
        const float* __restrict__ W, const float* __restrict__ a,
        short* __restrict__ hT, float* __restrict__ src, float* __restrict__ dst)
{
    __shared__ short tl[32][64];
    const int t = threadIdx.x, lane = t & 63, wv = t >> 6;
    const int row0 = blockIdx.x * 32;
    const int r0 = wv * 8;
    const float a1 = a[lane], a2 = a[FD + lane];

    float acc[8] = {0.f,0.f,0.f,0.f,0.f,0.f,0.f,0.f};
    for (int k0 = 0; k0 < FIN; k0 += 4) {
        const float w0 = W[(k0+0)*FD + lane];
        const float w1 = W[(k0+1)*FD + lane];
        const float w2 = W[(k0+2)*FD + lane];
        const float w3 = W[(k0+3)*FD + lane];
        #pragma unroll
        for (int r = 0; r < 8; ++r) {
            const float4 xv = *reinterpret_cast<const float4*>(&x[(size_t)(row0+r0+r)*FIN + k0]);
            acc[r] = fmaf(xv.x, w0, fmaf(xv.y, w1, fmaf(xv.z, w2, fmaf(xv.w, w3, acc[r]))));
        }
    }
    #pragma unroll
    for (int r = 0; r < 8; ++r) {
        tl[r0 + r][lane] = bf16bits(acc[r]);
        float p1 = acc[r] * a1, p2 = acc[r] * a2;
        #pragma unroll
        for (int s = 32; s > 0; s >>= 1) { p1 += __shfl_xor(p1, s); p2 += __shfl_xor(p2, s); }
        if (lane == 0) { src[row0 + r0 + r] = p1; dst[row0 + r0 + r] = p2; }
    }
    __syncthreads();
    // transpose out: thread t -> feature f = t>>2, rows (t&3)*8 .. +8
    const int f = t >> 2, rr = (t & 3) * 8;
    alignas(16) short tmp[8];
    #pragma unroll
    for (int k = 0; k < 8; ++k) tmp[k] = tl[rr + k][f];
    *reinterpret_cast<int4*>(&hT[(size_t)f * NN + row0 + rr]) = *reinterpret_cast<int4*>(tmp);
}

// ---------------- kernel 2: barrier-free fused gen + MFMA PV -----------------
// 512 blocks x 256 thr. Block = 16 rows, full j sweep. Wave w owns k-slice
// w*32..+32 of every 128-wide chunk; lane (l&15)=row, (l>>4)=k-group. GEN's
// s16x8 output IS the MFMA A-fragment (row=l&15, k=(l>>4)*8+e) -> weights go
// straight from registers into MFMA. Zero __syncthreads in the main loop, so
// the 1-ahead named-register prefetch stays in flight under GEN+MFMA.
// Per wave: 4 partial C fragments (one per 16-f tile), cross-wave k-reduce
// in LDS once at the end.
__global__ __launch_bounds__(256, 2) void k_attn(const int* __restrict__ adj,
        const short* __restrict__ hT, const float* __restrict__ src,
        const float* __restrict__ dst, float* __restrict__ out)
{
    __shared__ float cred[4][16][68];   // [wave][row][f] (+4 pad: no write conflicts)
    __shared__ float dred[4][16];

    const int t = threadIdx.x;
    const int i0 = blockIdx.x * IT;
    const int w   = t >> 6;          // wave = k-slice
    const int l   = t & 63;
    const int row = l & 15;          // A row / C col
    const int kg  = l >> 4;          // k-group
    const int cb  = w * 32 + kg * 8; // column base within chunk

    const float sv = src[i0 + row];
    float dsum = 0.f;
    f32x4 acc0 = {0.f,0.f,0.f,0.f}, acc1 = {0.f,0.f,0.f,0.f};
    f32x4 acc2 = {0.f,0.f,0.f,0.f}, acc3 = {0.f,0.f,0.f,0.f};

    const int4*   ap  = (const int4*)(adj + (size_t)(i0 + row) * NN + cb);
    const float4* dp  = (const float4*)(dst + cb);
    const int4*   hp0 = (const int4*)(hT + (size_t)(0*16 + row) * NN + cb);
    const int4*   hp1 = (const int4*)(hT + (size_t)(1*16 + row) * NN + cb);
    const int4*   hp2 = (const int4*)(hT + (size_t)(2*16 + row) * NN + cb);
    const int4*   hp3 = (const int4*)(hT + (size_t)(3*16 + row) * NN + cb);

#define GEN(A0,A1,D0,D1,PK) do { \
    const int   ai[8] = {(A0).x,(A0).y,(A0).z,(A0).w,(A1).x,(A1).y,(A1).z,(A1).w}; \
    const float di[8] = {(D0).x,(D0).y,(D0).z,(D0).w,(D1).x,(D1).y,(D1).z,(D1).w}; \
    _Pragma("unroll") \
    for (int e = 0; e < 8; ++e) { \
        float ev = sv + di[e]; \
        ev = fmaxf(ev, 0.2f * ev); \
        float wv_ = (ai[e] > 0) ? __expf(ev) : 0.f; \
        dsum += wv_; \
        (PK)[e] = bf16bits(wv_); \
    } \
} while (0)

#define LOADSET(S, guard) do { if (guard) { \
    a##S##0 = ap[0]; a##S##1 = ap[1]; \
    d##S##0 = dp[0]; d##S##1 = dp[1]; \
    h##S##0 = hp0[0]; h##S##1 = hp1[0]; h##S##2 = hp2[0]; h##S##3 = hp3[0]; \
    ap += 32; dp += 32; hp0 += 16; hp1 += 16; hp2 += 16; hp3 += 16; } \
} while (0)

#define MM(PK,H0,H1,H2,H3) do { \
    acc0 = __builtin_amdgcn_mfma_f32_16x16x32_bf16((PK), as_s16x8(H0), acc0, 0, 0, 0); \
    acc1 = __builtin_amdgcn_mfma_f32_16x16x32_bf16((PK), as_s16x8(H1), acc1, 0, 0, 0); \
    acc2 = __builtin_amdgcn_mfma_f32_16x16x32_bf16((PK), as_s16x8(H2), acc2, 0, 0, 0); \
    acc3 = __builtin_amdgcn_mfma_f32_16x16x32_bf16((PK), as_s16x8(H3), acc3, 0, 0, 0); \
} while (0)

    // prefetch chunk 0 into set A
    int4 aA0 = ap[0], aA1 = ap[1];
    float4 dA0 = dp[0], dA1 = dp[1];
    int4 hA0 = hp0[0], hA1 = hp1[0], hA2 = hp2[0], hA3 = hp3[0];
    ap += 32; dp += 32; hp0 += 16; hp1 += 16; hp2 += 16; hp3 += 16;
    int4 aB0, aB1; float4 dB0, dB1; int4 hB0, hB1, hB2, hB3;
    s16x8 pkA, pkB;

    for (int c = 0; c < NCH; c += 2) {
        LOADSET(B, (c + 1) < NCH);
        GEN(aA0, aA1, dA0, dA1, pkA);
        MM(pkA, hA0, hA1, hA2, hA3);
        LOADSET(A, (c + 2) < NCH);
        GEN(aB0, aB1, dB0, dB1, pkB);
        MM(pkB, hB0, hB1, hB2, hB3);
    }

#undef GEN
#undef LOADSET
#undef MM

    // denominator: sum the 4 k-groups of each row within the wave
    float d2 = dsum;
    d2 += __shfl_xor(d2, 16);
    d2 += __shfl_xor(d2, 32);
    if (kg == 0) dred[w][row] = d2;

    // C partials -> LDS
    #pragma unroll
    for (int j = 0; j < 4; ++j) {
        cred[w][kg*4 + j][0*16 + row] = acc0[j];
        cred[w][kg*4 + j][1*16 + row] = acc1[j];
        cred[w][kg*4 + j][2*16 + row] = acc2[j];
        cred[w][kg*4 + j][3*16 + row] = acc3[j];
    }
    __syncthreads();

    // combine across waves (k-slices), divide, ELU, store. thread t -> row t>>4,
    // f = (t&15)*4 .. +4  (coalesced float4 store)
    const int r  = t >> 4;
    const int f0 = (t & 15) * 4;
    const float den = dred[0][r] + dred[1][r] + dred[2][r] + dred[3][r];
    float4 o;
    float* op = (float*)&o;
    #pragma unroll
    for (int e = 0; e < 4; ++e) {
        float v = cred[0][r][f0+e] + cred[1][r][f0+e] + cred[2][r][f0+e] + cred[3][r][f0+e];
        v /= den;
        op[e] = (v > 0.f) ? v : expm1f(v);
    }
    *reinterpret_cast<float4*>(&out[(size_t)(i0 + r) * FD + f0]) = o;
}

extern "C" void kernel_launch(void* const* d_in, const int* in_sizes, int n_in,
                              void* d_out, int out_size, void* d_ws, size_t ws_size,
                              hipStream_t stream) {
    const float* x   = (const float*)d_in[0];
    const int*   adj = (const int*)d_in[1];
    const float* W   = (const float*)d_in[2];
    const float* a   = (const float*)d_in[3];
    float* out = (float*)d_out;

    short* hT  = (short*)d_ws;                                   // 64 x 8192 bf16 = 1 MB
    float* src = (float*)((char*)d_ws + (size_t)FD * NN * 2);    // 8192 f32
    float* dst = src + NN;                                       // 8192 f32

    k_proj<<<NN / 32, 256, 0, stream>>>(x, W, a, hT, src, dst);
    k_attn<<<NN / IT, 256, 0, stream>>>(adj, hT, src, dst, out);
}